// Round 11
// baseline (584.835 us; speedup 1.0000x reference)
//
#include <hip/hip_runtime.h>
#include <math.h>

#define HDIM 128

typedef __attribute__((ext_vector_type(8))) short    bf16x8;
typedef __attribute__((ext_vector_type(4))) float    f32x4;
typedef __attribute__((ext_vector_type(2))) float    f32x2;
typedef __attribute__((ext_vector_type(8))) unsigned short u16x8;
typedef __attribute__((ext_vector_type(4))) unsigned short u16x4;
typedef __attribute__((ext_vector_type(2))) __fp16 f16x2;   // matches cvt_pkrtz return type

__device__ __forceinline__ unsigned short f2bf(float f) {
    union { float f; unsigned int i; } c; c.f = f;
    unsigned int r = (c.i + 0x7fffu + ((c.i >> 16) & 1u)) >> 16;
    return (unsigned short)r;
}
// decode 8 fp8 (e4m3) packed in uint2 -> 4 packed f32 pairs
__device__ __forceinline__ void f8x8_decp(uint2 v, f32x2* p) {
    p[0] = __builtin_amdgcn_cvt_pk_f32_fp8((int)v.x, false);
    p[1] = __builtin_amdgcn_cvt_pk_f32_fp8((int)v.x, true);
    p[2] = __builtin_amdgcn_cvt_pk_f32_fp8((int)v.y, false);
    p[3] = __builtin_amdgcn_cvt_pk_f32_fp8((int)v.y, true);
}
// decode 16 fp8 (e4m3) packed in uint4 -> 8 f16 pairs
__device__ __forceinline__ void f8x16_dech(uint4 v, f16x2* h) {
    f32x2 p[8];
    p[0] = __builtin_amdgcn_cvt_pk_f32_fp8((int)v.x, false);
    p[1] = __builtin_amdgcn_cvt_pk_f32_fp8((int)v.x, true);
    p[2] = __builtin_amdgcn_cvt_pk_f32_fp8((int)v.y, false);
    p[3] = __builtin_amdgcn_cvt_pk_f32_fp8((int)v.y, true);
    p[4] = __builtin_amdgcn_cvt_pk_f32_fp8((int)v.z, false);
    p[5] = __builtin_amdgcn_cvt_pk_f32_fp8((int)v.z, true);
    p[6] = __builtin_amdgcn_cvt_pk_f32_fp8((int)v.w, false);
    p[7] = __builtin_amdgcn_cvt_pk_f32_fp8((int)v.w, true);
#pragma unroll
    for (int i = 0; i < 8; i++) h[i] = __builtin_amdgcn_cvt_pkrtz(p[i].x, p[i].y);
}
// packed relu: max(a, 0) on 2xf16 (v_pk_max_f16, inline const 0)
__device__ __forceinline__ f16x2 pkmax0(f16x2 a) {
    f16x2 r;
    asm("v_pk_max_f16 %0, %1, 0" : "=v"(r) : "v"(a));
    return r;
}
// per-edge partial dot over this lane's 16 feats (p in fp8 uint4)
__device__ __forceinline__ float edot16(uint4 pv, const f16x2 (&qh)[8], const f16x2 (&wh)[8]) {
    f16x2 ph[8]; f8x16_dech(pv, ph);
    float acc = 0.f;
#pragma unroll
    for (int i = 0; i < 8; i++)
        acc = __builtin_amdgcn_fdot2(pkmax0(ph[i] + qh[i]), wh[i], acc, false);
    return acc;
}
// fast sigmoid: rcp(1 + 2^(-x*log2e)); saturates correctly at +-inf
__device__ __forceinline__ float fsigmoid(float x) {
    float e = __builtin_amdgcn_exp2f(-x * 1.44269504f);
    return __builtin_amdgcn_rcpf(1.f + e);
}

// ---------------- weight prep (+ fold + cnt zeroing), one dispatch ----------------
struct WEnt { const float* src; unsigned short* dst; int K; };
struct WAll { WEnt w[5]; };

__global__ __launch_bounds__(256) void k_prep_all(
    WAll all, const float* __restrict__ We2, const float* __restrict__ be2,
    const float* __restrict__ Wc1, unsigned short* __restrict__ WtF,
    float* __restrict__ bF, int* __restrict__ cnt, int np)
{
    int y = blockIdx.y;
    int i = blockIdx.x * 256 + threadIdx.x;
    if (y == 5) {
        // fold encoder-2 into conv1: W' = We2@Wc1 (bf16 Wt layout), b' = be2@Wc1
        if (i < 128 * HDIM) {
            int c = i >> 7, k = i & 127;
            float s = 0.f;
            for (int j = 0; j < 128; j++)
                s += We2[k * 128 + j] * Wc1[j * 128 + c];
            WtF[(size_t)c * 128 + k] = f2bf(s);
            if (i < 128) {
                float b = 0.f;
                for (int j = 0; j < 128; j++) b += be2[j] * Wc1[j * 128 + i];
                bF[i] = b;
            }
        }
        return;
    }
    WEnt e = all.w[y];
    int lim = e.K * HDIM;
    if (i >= lim) {
        // idle threads of the K=128 slices (y=1..4) zero the degree counters
        if (y >= 1) {
            int zi = (y - 1) * 16384 + (i - 16384);
            if (zi >= 0 && zi < np) cnt[zi] = 0;
        }
        return;
    }
    int k = i >> 7, c = i & 127;
    e.dst[(size_t)c * e.K + k] = f2bf(e.src[i]);
}

// ---------------- CSR pass 1: node-level degree count (global atomics) ----------------
__global__ __launch_bounds__(256) void k_count(
    const int* __restrict__ dst, int* __restrict__ cnt, int E, int chunk)
{
    int beg = blockIdx.x * chunk;
    int fin = min(beg + chunk, E);
    for (int e = beg + threadIdx.x; e < fin; e += 256)
        atomicAdd(&cnt[dst[e]], 1);
}

// ---------------- CSR pass 2a: per-block (chunk<=256 nodes) local exclusive scan ----------------
__global__ __launch_bounds__(256) void k_scanA(
    const int* __restrict__ cnt, int* __restrict__ row_ptr, int* __restrict__ bsum,
    int n, int chunk)
{
    __shared__ int a[256], b[256];
    int blk = blockIdx.x, t = threadIdx.x;
    int n0 = blk * chunk;
    int m = min(chunk, n - n0);
    int v = (t < m) ? cnt[n0 + t] : 0;
    a[t] = v;
    __syncthreads();
    int* s1 = a; int* s2 = b;
    for (int off = 1; off < 256; off <<= 1) {
        s2[t] = s1[t] + ((t >= off) ? s1[t - off] : 0);
        __syncthreads();
        int* tmp = s1; s1 = s2; s2 = tmp;
    }
    if (t < m) row_ptr[n0 + t] = s1[t] - v;   // block-local exclusive
    if (t == 255) bsum[blk] = s1[255];
}

// ---------------- CSR pass 2b: scan of 256 block sums (+ w2 fp16 prep) ----------------
__global__ __launch_bounds__(256) void k_scanB(
    const int* __restrict__ bsum, int* __restrict__ bbase,
    const float* __restrict__ w2src, unsigned short* __restrict__ w2h)
{
    __shared__ int a[256], b[256];
    int t = threadIdx.x;
    if (t < 128) w2h[t] = __builtin_bit_cast(unsigned short, (__fp16)w2src[t]);
    int v = bsum[t];
    a[t] = v;
    __syncthreads();
    int* s1 = a; int* s2 = b;
    for (int off = 1; off < 256; off <<= 1) {
        s2[t] = s1[t] + ((t >= off) ? s1[t - off] : 0);
        __syncthreads();
        int* tmp = s1; s1 = s2; s2 = tmp;
    }
    bbase[t] = s1[t] - v;
}

// ---------------- CSR pass 2c: add block bases -> row_ptr, gcur, dis ----------------
__global__ __launch_bounds__(256) void k_scanC(
    const int* __restrict__ cnt, int* __restrict__ row_ptr, int* __restrict__ gcur,
    float* __restrict__ dis, const int* __restrict__ bbase, int n, int chunk, int E)
{
    int blk = blockIdx.x, t = threadIdx.x;
    int n0 = blk * chunk;
    int m = min(chunk, n - n0);
    if (t < m) {
        int node = n0 + t;
        int rp = row_ptr[node] + bbase[blk];
        row_ptr[node] = rp;
        gcur[node] = rp;
        dis[node] = rsqrtf(1.0f + (float)cnt[node]);
    }
    if (blk == 0 && t == 0) row_ptr[n] = E;
}

// ---------------- CSR pass 3: direct scatter into final col/epk ----------------
__global__ __launch_bounds__(256) void k_scatter(
    const int* __restrict__ src, const int* __restrict__ dst,
    int* __restrict__ gcur, int* __restrict__ col, uint2* __restrict__ epk,
    int E, int chunk)
{
    int beg = blockIdx.x * chunk;
    int fin = min(beg + chunk, E);
    for (int e = beg + threadIdx.x; e < fin; e += 256) {
        int s = src[e], d = dst[e];
        int pos = atomicAdd(&gcur[d], 1);
        col[pos] = s;
        epk[pos] = make_uint2((unsigned int)s, (unsigned int)e);
    }
}

// ---------------- MFMA GEMM (bf16 A), K=128; Wt staged in LDS (fragment order) ----------------
// out_mode: 0 = bf16, 1 = fp8(e4m3)
__global__ __launch_bounds__(256) void k_gemm_b(
    const unsigned short* __restrict__ X, const unsigned short* __restrict__ Wt,
    const float* __restrict__ bias, const float* __restrict__ scale,
    void* __restrict__ C, int M, int relu_out, int out_mode)
{
    __shared__ unsigned short sW[128 * 128];   // 32 KB
    const int t = threadIdx.x;
#pragma unroll
    for (int i = 0; i < 8; i++) {
        int c = t + i * 256;                 // 16-B chunk 0..2047 (row-major source)
        int row = c >> 4, o = c & 15;        // row 0..127, o = k-octet 0..15
        int mt = row >> 4, r = row & 15, kc = o >> 2, q = o & 3;
        int lidx = (mt * 4 + kc) * 64 + q * 16 + r;
        *(uint4*)(sW + (size_t)lidx * 8) = *(const uint4*)(Wt + (size_t)c * 8);
    }
    __syncthreads();
    int wave = t >> 6, lane = t & 63;
    int quad = lane >> 4, r = lane & 15;
    int row0 = blockIdx.x * 64 + wave * 16;
    if (row0 >= M) return;                   // M % 16 == 0: whole waves only
    const unsigned short* xp = X + (size_t)(row0 + r) * 128 + quad * 8;
    f32x4 acc[8];
#pragma unroll
    for (int mt = 0; mt < 8; mt++) acc[mt] = (f32x4){0.f, 0.f, 0.f, 0.f};
#pragma unroll
    for (int kc = 0; kc < 4; kc++) {
        bf16x8 xf = *(const bf16x8*)(xp + kc * 32);
#pragma unroll
        for (int mt = 0; mt < 8; mt++) {
            bf16x8 wf = *(const bf16x8*)(sW + ((size_t)((mt * 4 + kc) * 64 + lane)) * 8);
            acc[mt] = __builtin_amdgcn_mfma_f32_16x16x32_bf16(wf, xf, acc[mt], 0, 0, 0);
        }
    }
    float sc = scale ? scale[row0 + r] : 1.f;
    if (out_mode == 1) {
        unsigned char* cp = (unsigned char*)C + (size_t)(row0 + r) * HDIM + quad * 4;
#pragma unroll
        for (int mt = 0; mt < 8; mt++) {
            float v[4];
#pragma unroll
            for (int j = 0; j < 4; j++) {
                float x = acc[mt][j];
                if (bias) x += bias[mt * 16 + quad * 4 + j];
                if (relu_out) x = fmaxf(x, 0.f);
                v[j] = x * sc;
            }
            int wd = 0;
            wd = __builtin_amdgcn_cvt_pk_fp8_f32(v[0], v[1], wd, false);
            wd = __builtin_amdgcn_cvt_pk_fp8_f32(v[2], v[3], wd, true);
            *(unsigned int*)(cp + mt * 16) = (unsigned int)wd;
        }
    } else {
        unsigned short* cp = (unsigned short*)C + (size_t)(row0 + r) * HDIM + quad * 4;
#pragma unroll
        for (int mt = 0; mt < 8; mt++) {
            u16x4 o;
#pragma unroll
            for (int j = 0; j < 4; j++) {
                float v = acc[mt][j];
                if (bias) v += bias[mt * 16 + quad * 4 + j];
                if (relu_out) v = fmaxf(v, 0.f);
                o[j] = f2bf(v * sc);
            }
            *(u16x4*)(cp + mt * 16) = o;
        }
    }
}

// ---------------- fused P/Q GEMM: X read once, two W tiles in LDS, fp8 outs ----------------
__global__ __launch_bounds__(256) void k_gemm_pq(
    const unsigned short* __restrict__ X, const unsigned short* __restrict__ WtP,
    const unsigned short* __restrict__ WtQ, const float* __restrict__ biasP,
    unsigned char* __restrict__ P, unsigned char* __restrict__ Q, int M)
{
    __shared__ unsigned short sW[2 * 128 * 128];   // 64 KB
    const int t = threadIdx.x;
#pragma unroll
    for (int i = 0; i < 8; i++) {
        int c = t + i * 256;
        int row = c >> 4, o = c & 15;
        int mt = row >> 4, r = row & 15, kc = o >> 2, q = o & 3;
        int lidx = (mt * 4 + kc) * 64 + q * 16 + r;
        *(uint4*)(sW + (size_t)lidx * 8)         = *(const uint4*)(WtP + (size_t)c * 8);
        *(uint4*)(sW + 16384 + (size_t)lidx * 8) = *(const uint4*)(WtQ + (size_t)c * 8);
    }
    __syncthreads();
    int wave = t >> 6, lane = t & 63;
    int quad = lane >> 4, r = lane & 15;
    int row0 = blockIdx.x * 64 + wave * 16;
    if (row0 >= M) return;
    const unsigned short* xp = X + (size_t)(row0 + r) * 128 + quad * 8;
    f32x4 accP[8], accQ[8];
#pragma unroll
    for (int mt = 0; mt < 8; mt++) {
        accP[mt] = (f32x4){0.f, 0.f, 0.f, 0.f};
        accQ[mt] = (f32x4){0.f, 0.f, 0.f, 0.f};
    }
#pragma unroll
    for (int kc = 0; kc < 4; kc++) {
        bf16x8 xf = *(const bf16x8*)(xp + kc * 32);
#pragma unroll
        for (int mt = 0; mt < 8; mt++) {
            bf16x8 wfp = *(const bf16x8*)(sW + ((size_t)((mt * 4 + kc) * 64 + lane)) * 8);
            bf16x8 wfq = *(const bf16x8*)(sW + 16384 + ((size_t)((mt * 4 + kc) * 64 + lane)) * 8);
            accP[mt] = __builtin_amdgcn_mfma_f32_16x16x32_bf16(wfp, xf, accP[mt], 0, 0, 0);
            accQ[mt] = __builtin_amdgcn_mfma_f32_16x16x32_bf16(wfq, xf, accQ[mt], 0, 0, 0);
        }
    }
    unsigned char* pp = P + (size_t)(row0 + r) * HDIM + quad * 4;
    unsigned char* qp = Q + (size_t)(row0 + r) * HDIM + quad * 4;
#pragma unroll
    for (int mt = 0; mt < 8; mt++) {
        int wdp = 0, wdq = 0;
        float p0 = accP[mt][0] + biasP[mt * 16 + quad * 4 + 0];
        float p1 = accP[mt][1] + biasP[mt * 16 + quad * 4 + 1];
        float p2 = accP[mt][2] + biasP[mt * 16 + quad * 4 + 2];
        float p3 = accP[mt][3] + biasP[mt * 16 + quad * 4 + 3];
        wdp = __builtin_amdgcn_cvt_pk_fp8_f32(p0, p1, wdp, false);
        wdp = __builtin_amdgcn_cvt_pk_fp8_f32(p2, p3, wdp, true);
        wdq = __builtin_amdgcn_cvt_pk_fp8_f32(accQ[mt][0], accQ[mt][1], wdq, false);
        wdq = __builtin_amdgcn_cvt_pk_fp8_f32(accQ[mt][2], accQ[mt][3], wdq, true);
        *(unsigned int*)(pp + mt * 16) = (unsigned int)wdp;
        *(unsigned int*)(qp + mt * 16) = (unsigned int)wdq;
    }
}

// ---------------- MFMA GEMM (fp32 A = node_features), K=256; Wt staged in LDS ----------------
__global__ __launch_bounds__(256) void k_gemm_nf(
    const float* __restrict__ X, const unsigned short* __restrict__ Wt,
    const float* __restrict__ bias, unsigned short* __restrict__ C,
    int M, int relu_out)
{
    const int K = 256;
    __shared__ unsigned short sW[128 * 256];   // 64 KB
    const int t = threadIdx.x;
#pragma unroll
    for (int i = 0; i < 16; i++) {
        int c = t + i * 256;                 // 16-B chunk 0..4095
        int row = c >> 5, o = c & 31;        // row 0..127, o = k-octet 0..31
        int mt = row >> 4, r = row & 15, kc = o >> 2, q = o & 3;
        int lidx = (mt * 8 + kc) * 64 + q * 16 + r;
        *(uint4*)(sW + (size_t)lidx * 8) = *(const uint4*)(Wt + (size_t)c * 8);
    }
    __syncthreads();
    int wave = t >> 6, lane = t & 63;
    int quad = lane >> 4, r = lane & 15;
    int row0 = blockIdx.x * 64 + wave * 16;
    if (row0 >= M) return;
    const float* xp = X + (size_t)(row0 + r) * K + quad * 8;
    f32x4 acc[8];
#pragma unroll
    for (int mt = 0; mt < 8; mt++) acc[mt] = (f32x4){0.f, 0.f, 0.f, 0.f};
#pragma unroll 2
    for (int kc = 0; kc < 8; kc++) {
        float4 xa = *(const float4*)(xp + kc * 32);
        float4 xb = *(const float4*)(xp + kc * 32 + 4);
        bf16x8 xf;
        xf[0] = (short)f2bf(xa.x); xf[1] = (short)f2bf(xa.y);
        xf[2] = (short)f2bf(xa.z); xf[3] = (short)f2bf(xa.w);
        xf[4] = (short)f2bf(xb.x); xf[5] = (short)f2bf(xb.y);
        xf[6] = (short)f2bf(xb.z); xf[7] = (short)f2bf(xb.w);
#pragma unroll
        for (int mt = 0; mt < 8; mt++) {
            bf16x8 wf = *(const bf16x8*)(sW + ((size_t)((mt * 8 + kc) * 64 + lane)) * 8);
            acc[mt] = __builtin_amdgcn_mfma_f32_16x16x32_bf16(wf, xf, acc[mt], 0, 0, 0);
        }
    }
    unsigned short* cp = C + (size_t)(row0 + r) * HDIM + quad * 4;
#pragma unroll
    for (int mt = 0; mt < 8; mt++) {
        u16x4 o;
#pragma unroll
        for (int j = 0; j < 4; j++) {
            float v = acc[mt][j];
            if (bias) v += bias[mt * 16 + quad * 4 + j];
            if (relu_out) v = fmaxf(v, 0.f);
            o[j] = f2bf(v);
        }
        *(u16x4*)(cp + mt * 16) = o;
    }
}

// ---------------- aggregate (R3 shape: quad layout, 8-deep 8B gathers, packed f32 adds) ----------------
__global__ __launch_bounds__(256) void k_aggregate_f8(
    const int* __restrict__ row_ptr, const int* __restrict__ col,
    const float* __restrict__ dis, const uint2* __restrict__ y8,
    const float* __restrict__ bias, unsigned short* __restrict__ out, int n, int relu_out)
{
    int wid = (blockIdx.x * 256 + threadIdx.x) >> 6;
    if (wid >= n) return;
    int lane = threadIdx.x & 63;
    int q = lane >> 4, t = lane & 15;
    f32x2 acc[4];
    {
        uint2 sv = y8[(size_t)wid * 16 + t];        // self term y[i]
        f32x2 p[4]; f8x8_decp(sv, p);
#pragma unroll
        for (int i = 0; i < 4; i++) acc[i] = (q == 0) ? p[i] : (f32x2){0.f, 0.f};
    }
    int beg = row_ptr[wid], end = row_ptr[wid + 1];
    int j = beg + q;
    // 8 independent gathers in flight
    for (; j + 28 < end; j += 32) {
        int s[8];
        uint2 v[8];
#pragma unroll
        for (int u = 0; u < 8; u++) s[u] = col[j + u * 4];
#pragma unroll
        for (int u = 0; u < 8; u++) v[u] = y8[(size_t)s[u] * 16 + t];
#pragma unroll
        for (int u = 0; u < 8; u++) {
            f32x2 p[4]; f8x8_decp(v[u], p);
#pragma unroll
            for (int i = 0; i < 4; i++) acc[i] += p[i];   // v_pk_add_f32
        }
    }
    for (; j + 12 < end; j += 16) {
        int s0 = col[j], s1 = col[j + 4], s2 = col[j + 8], s3 = col[j + 12];
        uint2 v0 = y8[(size_t)s0 * 16 + t];
        uint2 v1 = y8[(size_t)s1 * 16 + t];
        uint2 v2 = y8[(size_t)s2 * 16 + t];
        uint2 v3 = y8[(size_t)s3 * 16 + t];
        f32x2 p0[4], p1[4], p2[4], p3[4];
        f8x8_decp(v0, p0); f8x8_decp(v1, p1); f8x8_decp(v2, p2); f8x8_decp(v3, p3);
#pragma unroll
        for (int i = 0; i < 4; i++) acc[i] += (p0[i] + p1[i]) + (p2[i] + p3[i]);
    }
    for (; j < end; j += 4) {
        int s = col[j];
        uint2 v = y8[(size_t)s * 16 + t];
        f32x2 p[4]; f8x8_decp(v, p);
#pragma unroll
        for (int i = 0; i < 4; i++) acc[i] += p[i];
    }
#pragma unroll
    for (int i = 0; i < 4; i++) {
        acc[i].x += __shfl_xor(acc[i].x, 16, 64);
        acc[i].y += __shfl_xor(acc[i].y, 16, 64);
        acc[i].x += __shfl_xor(acc[i].x, 32, 64);
        acc[i].y += __shfl_xor(acc[i].y, 32, 64);
    }
    if (q == 0) {
        float di = dis[wid];
        u16x8 o;
#pragma unroll
        for (int i = 0; i < 4; i++) {
            float v0 = di * acc[i].x + bias[t * 8 + i * 2];
            float v1 = di * acc[i].y + bias[t * 8 + i * 2 + 1];
            if (relu_out) { v0 = fmaxf(v0, 0.f); v1 = fmaxf(v1, 0.f); }
            o[i * 2]     = f2bf(v0);
            o[i * 2 + 1] = f2bf(v1);
        }
        *(u16x8*)(out + (size_t)wid * HDIM + t * 8) = o;
    }
}

// ---------------- edge scorer: 8 groups of 8 lanes, 2-deep 16B gathers, fast sigmoid ----------------
__global__ __launch_bounds__(256) void k_edge_score_csr(
    const int* __restrict__ row_ptr, const uint2* __restrict__ epk,
    const uint4* __restrict__ P8, const uint4* __restrict__ Q8,
    const unsigned short* __restrict__ w2h, const float* __restrict__ b2,
    float* __restrict__ out, int n)
{
    int wid = (blockIdx.x * 256 + threadIdx.x) >> 6;
    if (wid >= n) return;
    int lane = threadIdx.x & 63;
    unsigned g = (unsigned)(lane >> 3), t = (unsigned)(lane & 7);
    f16x2 wh[8], qh[8];
    {
        uint4 wv0 = *(const uint4*)(w2h + t * 16);
        uint4 wv1 = *(const uint4*)(w2h + t * 16 + 8);
        wh[0] = __builtin_bit_cast(f16x2, wv0.x);
        wh[1] = __builtin_bit_cast(f16x2, wv0.y);
        wh[2] = __builtin_bit_cast(f16x2, wv0.z);
        wh[3] = __builtin_bit_cast(f16x2, wv0.w);
        wh[4] = __builtin_bit_cast(f16x2, wv1.x);
        wh[5] = __builtin_bit_cast(f16x2, wv1.y);
        wh[6] = __builtin_bit_cast(f16x2, wv1.z);
        wh[7] = __builtin_bit_cast(f16x2, wv1.w);
        uint4 qv = Q8[(unsigned)wid * 8u + t];   // Q row, sequential per node, shared by groups
        f8x16_dech(qv, qh);
    }
    float bb = b2[0];
    int beg = row_ptr[wid], end = row_ptr[wid + 1];
    int j = beg + (int)g;
    // 2 edges per group in flight (16 gathers/iter across wave) — R4/R6-verified shape
    for (; j + 8 < end; j += 16) {
        uint2 e0 = epk[j], e1 = epk[j + 8];
        uint4 p0 = P8[e0.x * 8u + t];
        uint4 p1 = P8[e1.x * 8u + t];
        float s0 = edot16(p0, qh, wh);
        float s1 = edot16(p1, qh, wh);
        s0 += __shfl_xor(s0, 4, 8); s1 += __shfl_xor(s1, 4, 8);
        s0 += __shfl_xor(s0, 2, 8); s1 += __shfl_xor(s1, 2, 8);
        s0 += __shfl_xor(s0, 1, 8); s1 += __shfl_xor(s1, 1, 8);
        // every lane of the group has both sums; lane t scores edge t
        float sv = (t == 0) ? s0 : s1;
        unsigned eid = (t == 0) ? e0.y : e1.y;
        if (t < 2)
            __builtin_nontemporal_store(fsigmoid(sv + bb), &out[eid]);   // NT: keep L2 for P
    }
    if (j < end) {
        uint2 e0 = epk[j];
        uint4 p0 = P8[e0.x * 8u + t];
        float s0 = edot16(p0, qh, wh);
        s0 += __shfl_xor(s0, 4, 8);
        s0 += __shfl_xor(s0, 2, 8);
        s0 += __shfl_xor(s0, 1, 8);
        if (t == 0)
            __builtin_nontemporal_store(fsigmoid(s0 + bb), &out[e0.y]);
    }
}

extern "C" void kernel_launch(void* const* d_in, const int* in_sizes, int n_in,
                              void* d_out, int out_size, void* d_ws, size_t ws_size,
                              hipStream_t stream) {
    const float* nf   = (const float*)d_in[0];
    const int*   ei   = (const int*)d_in[1];
    const float* ew1  = (const float*)d_in[2];
    const float* eb1  = (const float*)d_in[3];
    const float* ew2  = (const float*)d_in[4];
    const float* eb2  = (const float*)d_in[5];
    const float* cw1  = (const float*)d_in[6];
    const float* cb1  = (const float*)d_in[7];
    const float* cw2  = (const float*)d_in[8];
    const float* cb2  = (const float*)d_in[9];
    const float* cw3  = (const float*)d_in[10];
    const float* cb3  = (const float*)d_in[11];
    const float* clw1 = (const float*)d_in[12];
    const float* clb1 = (const float*)d_in[13];
    const float* clw2 = (const float*)d_in[14];
    const float* clb2 = (const float*)d_in[15];
    float* out = (float*)d_out;

    const int FD = 256;
    const int N = in_sizes[0] / FD;
    const int E = in_sizes[1] / 2;
    const int PBLK = 256;
    const int chunkE = (E + PBLK - 1) / PBLK;
    const int chunkN = (N + 255) / 256;          // <=256 required (N <= 65536)

    size_t Np = ((size_t)N + 256) & ~(size_t)255;
    char* w = (char*)d_ws;
    float* dis     = (float*)w;            w += Np * 4;
    int*   cnt     = (int*)w;              w += Np * 4;
    int*   gcur    = (int*)w;              w += Np * 4;
    int*   row_ptr = (int*)w;              w += Np * 4;
    int*   bsum    = (int*)w;              w += 256 * 4;
    int*   bbase   = (int*)w;              w += 256 * 4;
    uint2* epk     = (uint2*)w;            w += (size_t)E * 8;
    int*   col     = (int*)w;              w += (((size_t)E * 4) + 255) & ~(size_t)255;
    unsigned short* bufA = (unsigned short*)w;  w += (size_t)N * HDIM * 2;
    unsigned short* bufB = (unsigned short*)w;  w += (size_t)N * HDIM * 2;
    unsigned short* bufC = (unsigned short*)w;  w += (size_t)N * HDIM * 2;
    unsigned char*  f8X  = (unsigned char*)w;   w += ((size_t)N * HDIM + 255) & ~(size_t)255;
    unsigned char*  f8P  = (unsigned char*)w;   w += ((size_t)N * HDIM + 255) & ~(size_t)255;
    unsigned char*  f8Q  = (unsigned char*)w;   w += ((size_t)N * HDIM + 255) & ~(size_t)255;
    unsigned short* wtE1 = (unsigned short*)w;  w += 256 * HDIM * 2;
    unsigned short* wtF  = (unsigned short*)w;  w += 128 * HDIM * 2;   // folded We2@Wc1
    unsigned short* wtC2 = (unsigned short*)w;  w += 128 * HDIM * 2;
    unsigned short* wtC3 = (unsigned short*)w;  w += 128 * HDIM * 2;
    unsigned short* wtT  = (unsigned short*)w;  w += 128 * HDIM * 2;
    unsigned short* wtB  = (unsigned short*)w;  w += 128 * HDIM * 2;
    unsigned short* w2h  = (unsigned short*)w;  w += 256 * 2;
    float*          bF   = (float*)w;           w += 128 * 4;

    int gemm_grid = (N + 63) / 64;
    int ag = (N + 3) / 4;

    // ---- weight prep + fold + cnt zeroing (one dispatch) ----
    WAll wa;
    wa.w[0] = { ew1,               wtE1, 256 };
    wa.w[1] = { cw2,               wtC2, 128 };
    wa.w[2] = { cw3,               wtC3, 128 };
    wa.w[3] = { clw1,              wtT,  128 };
    wa.w[4] = { clw1 + 128 * HDIM, wtB,  128 };
    k_prep_all<<<dim3(128, 6), 256, 0, stream>>>(wa, ew2, eb2, cw1, wtF, bF, cnt, (int)Np);

    // ---- CSR build: direct node-level counting sort (no bucket staging) ----
    k_count<<<PBLK, 256, 0, stream>>>(ei + E, cnt, E, chunkE);
    k_scanA<<<256, 256, 0, stream>>>(cnt, row_ptr, bsum, N, chunkN);
    k_scanB<<<1, 256, 0, stream>>>(bsum, bbase, clw2, w2h);
    k_scanC<<<256, 256, 0, stream>>>(cnt, row_ptr, gcur, dis, bbase, N, chunkN, E);
    k_scatter<<<PBLK, 256, 0, stream>>>(ei, ei + E, gcur, col, epk, E, chunkE);

    // ---- encoder stage 1 (bf16, relu) ----
    k_gemm_nf<<<gemm_grid, 256, 0, stream>>>(nf, wtE1, eb1, bufA, N, 1);

    // ---- conv1 (encoder-2 folded in): y = dis*(xe@W' + b') as fp8; aggregate -> bf16 ----
    k_gemm_b<<<gemm_grid, 256, 0, stream>>>(bufA, wtF, bF, dis, f8X, N, 0, 1);
    k_aggregate_f8<<<ag, 256, 0, stream>>>(row_ptr, col, dis, (const uint2*)f8X, cb1, bufC, N, 1);
    // ---- conv2 ----
    k_gemm_b<<<gemm_grid, 256, 0, stream>>>(bufC, wtC2, nullptr, dis, f8X, N, 0, 1);
    k_aggregate_f8<<<ag, 256, 0, stream>>>(row_ptr, col, dis, (const uint2*)f8X, cb2, bufA, N, 1);
    // ---- conv3 (no relu) ----
    k_gemm_b<<<gemm_grid, 256, 0, stream>>>(bufA, wtC3, nullptr, dis, f8X, N, 0, 1);
    k_aggregate_f8<<<ag, 256, 0, stream>>>(row_ptr, col, dis, (const uint2*)f8X, cb3, bufB, N, 0); // x3

    // ---- edge classifier: fused P/Q GEMM (X read once) ----
    k_gemm_pq<<<gemm_grid, 256, 0, stream>>>(bufB, wtT, wtB, clb1, f8P, f8Q, N);

    // ---- scorer: wave per dst node (Q streamed once per node, P random, NT out) ----
    k_edge_score_csr<<<ag, 256, 0, stream>>>(row_ptr, epk, (const uint4*)f8P, (const uint4*)f8Q,
                                             w2h, clb2, out, N);
}

// Round 12
// 439.029 us; speedup vs baseline: 1.3321x; 1.3321x over previous
//
#include <hip/hip_runtime.h>
#include <math.h>

#define HDIM 128
#define BSH 7                 // bucket = dst >> 7 (128 nodes per bucket)
#define MAXBUCK 512

typedef __attribute__((ext_vector_type(8))) short    bf16x8;
typedef __attribute__((ext_vector_type(4))) float    f32x4;
typedef __attribute__((ext_vector_type(2))) float    f32x2;
typedef __attribute__((ext_vector_type(8))) unsigned short u16x8;
typedef __attribute__((ext_vector_type(4))) unsigned short u16x4;
typedef __attribute__((ext_vector_type(2))) __fp16 f16x2;   // matches cvt_pkrtz return type

__device__ __forceinline__ unsigned short f2bf(float f) {
    union { float f; unsigned int i; } c; c.f = f;
    unsigned int r = (c.i + 0x7fffu + ((c.i >> 16) & 1u)) >> 16;
    return (unsigned short)r;
}
// decode 8 fp8 (e4m3) packed in uint2 -> 4 packed f32 pairs
__device__ __forceinline__ void f8x8_decp(uint2 v, f32x2* p) {
    p[0] = __builtin_amdgcn_cvt_pk_f32_fp8((int)v.x, false);
    p[1] = __builtin_amdgcn_cvt_pk_f32_fp8((int)v.x, true);
    p[2] = __builtin_amdgcn_cvt_pk_f32_fp8((int)v.y, false);
    p[3] = __builtin_amdgcn_cvt_pk_f32_fp8((int)v.y, true);
}
// decode 16 fp8 (e4m3) packed in uint4 -> 8 f16 pairs
__device__ __forceinline__ void f8x16_dech(uint4 v, f16x2* h) {
    f32x2 p[8];
    p[0] = __builtin_amdgcn_cvt_pk_f32_fp8((int)v.x, false);
    p[1] = __builtin_amdgcn_cvt_pk_f32_fp8((int)v.x, true);
    p[2] = __builtin_amdgcn_cvt_pk_f32_fp8((int)v.y, false);
    p[3] = __builtin_amdgcn_cvt_pk_f32_fp8((int)v.y, true);
    p[4] = __builtin_amdgcn_cvt_pk_f32_fp8((int)v.z, false);
    p[5] = __builtin_amdgcn_cvt_pk_f32_fp8((int)v.z, true);
    p[6] = __builtin_amdgcn_cvt_pk_f32_fp8((int)v.w, false);
    p[7] = __builtin_amdgcn_cvt_pk_f32_fp8((int)v.w, true);
#pragma unroll
    for (int i = 0; i < 8; i++) h[i] = __builtin_amdgcn_cvt_pkrtz(p[i].x, p[i].y);
}
// packed relu: max(a, 0) on 2xf16 (v_pk_max_f16, inline const 0)
__device__ __forceinline__ f16x2 pkmax0(f16x2 a) {
    f16x2 r;
    asm("v_pk_max_f16 %0, %1, 0" : "=v"(r) : "v"(a));
    return r;
}
// per-edge partial dot over this lane's 16 feats (p in fp8 uint4)
__device__ __forceinline__ float edot16(uint4 pv, const f16x2 (&qh)[8], const f16x2 (&wh)[8]) {
    f16x2 ph[8]; f8x16_dech(pv, ph);
    float acc = 0.f;
#pragma unroll
    for (int i = 0; i < 8; i++)
        acc = __builtin_amdgcn_fdot2(pkmax0(ph[i] + qh[i]), wh[i], acc, false);
    return acc;
}
// fast sigmoid: rcp(1 + 2^(-x*log2e)); saturates correctly at +-inf
__device__ __forceinline__ float fsigmoid(float x) {
    float e = __builtin_amdgcn_exp2f(-x * 1.44269504f);
    return __builtin_amdgcn_rcpf(1.f + e);
}

// ---------------- weight prep (+ fold + tot zeroing), one dispatch ----------------
struct WEnt { const float* src; unsigned short* dst; int K; };
struct WAll { WEnt w[5]; };

__global__ __launch_bounds__(256) void k_prep_all(
    WAll all, const float* __restrict__ We2, const float* __restrict__ be2,
    const float* __restrict__ Wc1, unsigned short* __restrict__ WtF,
    float* __restrict__ bF, int* __restrict__ tot)
{
    int y = blockIdx.y;
    int i = blockIdx.x * 256 + threadIdx.x;
    if (y == 5) {
        // fold encoder-2 into conv1: W' = We2@Wc1 (bf16 Wt layout), b' = be2@Wc1
        if (i < 128 * HDIM) {
            int c = i >> 7, k = i & 127;
            float s = 0.f;
            for (int j = 0; j < 128; j++)
                s += We2[k * 128 + j] * Wc1[j * 128 + c];
            WtF[(size_t)c * 128 + k] = f2bf(s);
            if (i < 128) {
                float b = 0.f;
                for (int j = 0; j < 128; j++) b += be2[j] * Wc1[j * 128 + i];
                bF[i] = b;
            }
        }
        return;
    }
    WEnt e = all.w[y];
    int lim = e.K * HDIM;
    if (i >= lim) {
        // idle threads of the y=1 slice zero the bucket totals
        if (y == 1) {
            int zi = i - lim;
            if (zi < MAXBUCK) tot[zi] = 0;
        }
        return;
    }
    int k = i >> 7, c = i & 127;
    e.dst[(size_t)c * e.K + k] = f2bf(e.src[i]);
}

// ---------------- CSR stage 1: per-block bucket histograms ----------------
__global__ __launch_bounds__(256) void k_hist(
    const int* __restrict__ dst, int* __restrict__ tot,
    int* __restrict__ hist, int E, int chunk, int nbuck)
{
    __shared__ int h[MAXBUCK];
    for (int i = threadIdx.x; i < MAXBUCK; i += 256) h[i] = 0;
    __syncthreads();
    int beg = blockIdx.x * chunk;
    int fin = min(beg + chunk, E);
    for (int e = beg + threadIdx.x; e < fin; e += 256)
        atomicAdd(&h[dst[e] >> BSH], 1);
    __syncthreads();
    for (int k = threadIdx.x; k < nbuck; k += 256) {
        int v = h[k];
        hist[(size_t)blockIdx.x * nbuck + k] = v;
        if (v) atomicAdd(&tot[k], v);
    }
}

// ---------------- CSR stage 2: exclusive scan of bucket totals (+ w2 fp16 prep) ----------------
__global__ __launch_bounds__(256) void k_scan_buckets(
    const int* __restrict__ tot, int* __restrict__ gcur, int* __restrict__ base, int nbuck,
    const float* __restrict__ w2src, unsigned short* __restrict__ w2h)
{
    __shared__ int a[MAXBUCK], b[MAXBUCK];
    int t = threadIdx.x;
    if (t < 128) w2h[t] = __builtin_bit_cast(unsigned short, (__fp16)w2src[t]);
    for (int i = t; i < MAXBUCK; i += 256) a[i] = (i < nbuck) ? tot[i] : 0;
    __syncthreads();
    int* s1 = a; int* s2 = b;
    for (int off = 1; off < MAXBUCK; off <<= 1) {
        for (int i = t; i < MAXBUCK; i += 256)
            s2[i] = s1[i] + ((i >= off) ? s1[i - off] : 0);
        __syncthreads();
        int* tmp = s1; s1 = s2; s2 = tmp;
    }
    for (int i = t; i < nbuck; i += 256) {
        int e = (i == 0) ? 0 : s1[i - 1];
        gcur[i] = e;
        base[i] = e;
    }
    if (t == 0) base[nbuck] = s1[nbuck - 1];
}

// ---------------- CSR stage 3: partition edges into bucket segments ----------------
// staging entry: { src | (dst<<16), edge_id }  (N < 65536)
__global__ __launch_bounds__(256) void k_partition(
    const int* __restrict__ src, const int* __restrict__ dst,
    const int* __restrict__ hist, int* __restrict__ gcur,
    uint2* __restrict__ stag, int E, int chunk, int nbuck)
{
    __shared__ int h[MAXBUCK];
    int t = threadIdx.x;
    for (int k = t; k < nbuck; k += 256) {
        int v = hist[(size_t)blockIdx.x * nbuck + k];
        h[k] = v ? atomicAdd(&gcur[k], v) : 0;
    }
    __syncthreads();
    int beg = blockIdx.x * chunk;
    int fin = min(beg + chunk, E);
    for (int e = beg + t; e < fin; e += 256) {
        unsigned int d = (unsigned int)dst[e];
        unsigned int s = (unsigned int)src[e];
        int pos = atomicAdd(&h[d >> BSH], 1);
        stag[pos] = make_uint2(s | (d << 16), (unsigned int)e);
    }
}

// ---------------- CSR stage 4: per-bucket counts + row_ptr + col/epk scatter + dis ----------------
// col[pos] = src (4B, for aggregates); epk[pos] = { src, edge_id } (for scorer).
__global__ __launch_bounds__(256) void k_bucket_csr(
    const int* __restrict__ base, const uint2* __restrict__ stag,
    int* __restrict__ row_ptr, int* __restrict__ col, uint2* __restrict__ epk,
    float* __restrict__ dis, int n, int nbuck)
{
    __shared__ int cl[128], sa[128], sb[128], cur[128];
    int k = blockIdx.x;
    int n0 = k << BSH;
    int t = threadIdx.x;
    if (t < 128) cl[t] = 0;
    __syncthreads();
    int b0 = base[k];
    int m = base[k + 1] - b0;
    const uint2* seg = stag + b0;
    for (int i = t; i < m; i += 256) atomicAdd(&cl[(seg[i].x >> 16) & 127], 1);
    __syncthreads();
    int cv = 0;
    if (t < 128) { cv = cl[t]; sa[t] = cv; }
    __syncthreads();
    int* s1 = sa; int* s2 = sb;
    for (int off = 1; off < 128; off <<= 1) {
        if (t < 128) s2[t] = s1[t] + ((t >= off) ? s1[t - off] : 0);
        __syncthreads();
        int* tmp = s1; s1 = s2; s2 = tmp;
    }
    if (t < 128) {
        int node = n0 + t;
        if (node < n) {
            int rpv = b0 + s1[t] - cv;
            row_ptr[node] = rpv;
            cur[t] = rpv;
            dis[node] = rsqrtf(1.0f + (float)cv);
        }
    }
    if (k == 0 && t == 0) row_ptr[n] = base[nbuck];
    __syncthreads();
    for (int i = t; i < m; i += 256) {
        uint2 e = seg[i];
        int pos = atomicAdd(&cur[(e.x >> 16) & 127], 1);
        int s = (int)(e.x & 0xffffu);
        col[pos] = s;
        epk[pos] = make_uint2((unsigned int)s, e.y);
    }
}

// ---------------- MFMA GEMM (bf16 A), K=128; Wt staged in LDS (fragment order) ----------------
// out_mode: 0 = bf16, 1 = fp8(e4m3)
__global__ __launch_bounds__(256) void k_gemm_b(
    const unsigned short* __restrict__ X, const unsigned short* __restrict__ Wt,
    const float* __restrict__ bias, const float* __restrict__ scale,
    void* __restrict__ C, int M, int relu_out, int out_mode)
{
    __shared__ unsigned short sW[128 * 128];   // 32 KB
    const int t = threadIdx.x;
#pragma unroll
    for (int i = 0; i < 8; i++) {
        int c = t + i * 256;                 // 16-B chunk 0..2047 (row-major source)
        int row = c >> 4, o = c & 15;        // row 0..127, o = k-octet 0..15
        int mt = row >> 4, r = row & 15, kc = o >> 2, q = o & 3;
        int lidx = (mt * 4 + kc) * 64 + q * 16 + r;
        *(uint4*)(sW + (size_t)lidx * 8) = *(const uint4*)(Wt + (size_t)c * 8);
    }
    __syncthreads();
    int wave = t >> 6, lane = t & 63;
    int quad = lane >> 4, r = lane & 15;
    int row0 = blockIdx.x * 64 + wave * 16;
    if (row0 >= M) return;                   // M % 16 == 0: whole waves only
    const unsigned short* xp = X + (size_t)(row0 + r) * 128 + quad * 8;
    f32x4 acc[8];
#pragma unroll
    for (int mt = 0; mt < 8; mt++) acc[mt] = (f32x4){0.f, 0.f, 0.f, 0.f};
#pragma unroll
    for (int kc = 0; kc < 4; kc++) {
        bf16x8 xf = *(const bf16x8*)(xp + kc * 32);
#pragma unroll
        for (int mt = 0; mt < 8; mt++) {
            bf16x8 wf = *(const bf16x8*)(sW + ((size_t)((mt * 4 + kc) * 64 + lane)) * 8);
            acc[mt] = __builtin_amdgcn_mfma_f32_16x16x32_bf16(wf, xf, acc[mt], 0, 0, 0);
        }
    }
    float sc = scale ? scale[row0 + r] : 1.f;
    if (out_mode == 1) {
        unsigned char* cp = (unsigned char*)C + (size_t)(row0 + r) * HDIM + quad * 4;
#pragma unroll
        for (int mt = 0; mt < 8; mt++) {
            float v[4];
#pragma unroll
            for (int j = 0; j < 4; j++) {
                float x = acc[mt][j];
                if (bias) x += bias[mt * 16 + quad * 4 + j];
                if (relu_out) x = fmaxf(x, 0.f);
                v[j] = x * sc;
            }
            int wd = 0;
            wd = __builtin_amdgcn_cvt_pk_fp8_f32(v[0], v[1], wd, false);
            wd = __builtin_amdgcn_cvt_pk_fp8_f32(v[2], v[3], wd, true);
            *(unsigned int*)(cp + mt * 16) = (unsigned int)wd;
        }
    } else {
        unsigned short* cp = (unsigned short*)C + (size_t)(row0 + r) * HDIM + quad * 4;
#pragma unroll
        for (int mt = 0; mt < 8; mt++) {
            u16x4 o;
#pragma unroll
            for (int j = 0; j < 4; j++) {
                float v = acc[mt][j];
                if (bias) v += bias[mt * 16 + quad * 4 + j];
                if (relu_out) v = fmaxf(v, 0.f);
                o[j] = f2bf(v * sc);
            }
            *(u16x4*)(cp + mt * 16) = o;
        }
    }
}

// ---------------- fused P/Q GEMM: X read once, two W tiles in LDS, fp8 outs ----------------
__global__ __launch_bounds__(256) void k_gemm_pq(
    const unsigned short* __restrict__ X, const unsigned short* __restrict__ WtP,
    const unsigned short* __restrict__ WtQ, const float* __restrict__ biasP,
    unsigned char* __restrict__ P, unsigned char* __restrict__ Q, int M)
{
    __shared__ unsigned short sW[2 * 128 * 128];   // 64 KB
    const int t = threadIdx.x;
#pragma unroll
    for (int i = 0; i < 8; i++) {
        int c = t + i * 256;
        int row = c >> 4, o = c & 15;
        int mt = row >> 4, r = row & 15, kc = o >> 2, q = o & 3;
        int lidx = (mt * 4 + kc) * 64 + q * 16 + r;
        *(uint4*)(sW + (size_t)lidx * 8)         = *(const uint4*)(WtP + (size_t)c * 8);
        *(uint4*)(sW + 16384 + (size_t)lidx * 8) = *(const uint4*)(WtQ + (size_t)c * 8);
    }
    __syncthreads();
    int wave = t >> 6, lane = t & 63;
    int quad = lane >> 4, r = lane & 15;
    int row0 = blockIdx.x * 64 + wave * 16;
    if (row0 >= M) return;
    const unsigned short* xp = X + (size_t)(row0 + r) * 128 + quad * 8;
    f32x4 accP[8], accQ[8];
#pragma unroll
    for (int mt = 0; mt < 8; mt++) {
        accP[mt] = (f32x4){0.f, 0.f, 0.f, 0.f};
        accQ[mt] = (f32x4){0.f, 0.f, 0.f, 0.f};
    }
#pragma unroll
    for (int kc = 0; kc < 4; kc++) {
        bf16x8 xf = *(const bf16x8*)(xp + kc * 32);
#pragma unroll
        for (int mt = 0; mt < 8; mt++) {
            bf16x8 wfp = *(const bf16x8*)(sW + ((size_t)((mt * 4 + kc) * 64 + lane)) * 8);
            bf16x8 wfq = *(const bf16x8*)(sW + 16384 + ((size_t)((mt * 4 + kc) * 64 + lane)) * 8);
            accP[mt] = __builtin_amdgcn_mfma_f32_16x16x32_bf16(wfp, xf, accP[mt], 0, 0, 0);
            accQ[mt] = __builtin_amdgcn_mfma_f32_16x16x32_bf16(wfq, xf, accQ[mt], 0, 0, 0);
        }
    }
    unsigned char* pp = P + (size_t)(row0 + r) * HDIM + quad * 4;
    unsigned char* qp = Q + (size_t)(row0 + r) * HDIM + quad * 4;
#pragma unroll
    for (int mt = 0; mt < 8; mt++) {
        int wdp = 0, wdq = 0;
        float p0 = accP[mt][0] + biasP[mt * 16 + quad * 4 + 0];
        float p1 = accP[mt][1] + biasP[mt * 16 + quad * 4 + 1];
        float p2 = accP[mt][2] + biasP[mt * 16 + quad * 4 + 2];
        float p3 = accP[mt][3] + biasP[mt * 16 + quad * 4 + 3];
        wdp = __builtin_amdgcn_cvt_pk_fp8_f32(p0, p1, wdp, false);
        wdp = __builtin_amdgcn_cvt_pk_fp8_f32(p2, p3, wdp, true);
        wdq = __builtin_amdgcn_cvt_pk_fp8_f32(accQ[mt][0], accQ[mt][1], wdq, false);
        wdq = __builtin_amdgcn_cvt_pk_fp8_f32(accQ[mt][2], accQ[mt][3], wdq, true);
        *(unsigned int*)(pp + mt * 16) = (unsigned int)wdp;
        *(unsigned int*)(qp + mt * 16) = (unsigned int)wdq;
    }
}

// ---------------- MFMA GEMM (fp32 A = node_features), K=256; Wt staged in LDS ----------------
__global__ __launch_bounds__(256) void k_gemm_nf(
    const float* __restrict__ X, const unsigned short* __restrict__ Wt,
    const float* __restrict__ bias, unsigned short* __restrict__ C,
    int M, int relu_out)
{
    const int K = 256;
    __shared__ unsigned short sW[128 * 256];   // 64 KB
    const int t = threadIdx.x;
#pragma unroll
    for (int i = 0; i < 16; i++) {
        int c = t + i * 256;                 // 16-B chunk 0..4095
        int row = c >> 5, o = c & 31;        // row 0..127, o = k-octet 0..31
        int mt = row >> 4, r = row & 15, kc = o >> 2, q = o & 3;
        int lidx = (mt * 8 + kc) * 64 + q * 16 + r;
        *(uint4*)(sW + (size_t)lidx * 8) = *(const uint4*)(Wt + (size_t)c * 8);
    }
    __syncthreads();
    int wave = t >> 6, lane = t & 63;
    int quad = lane >> 4, r = lane & 15;
    int row0 = blockIdx.x * 64 + wave * 16;
    if (row0 >= M) return;
    const float* xp = X + (size_t)(row0 + r) * K + quad * 8;
    f32x4 acc[8];
#pragma unroll
    for (int mt = 0; mt < 8; mt++) acc[mt] = (f32x4){0.f, 0.f, 0.f, 0.f};
#pragma unroll 2
    for (int kc = 0; kc < 8; kc++) {
        float4 xa = *(const float4*)(xp + kc * 32);
        float4 xb = *(const float4*)(xp + kc * 32 + 4);
        bf16x8 xf;
        xf[0] = (short)f2bf(xa.x); xf[1] = (short)f2bf(xa.y);
        xf[2] = (short)f2bf(xa.z); xf[3] = (short)f2bf(xa.w);
        xf[4] = (short)f2bf(xb.x); xf[5] = (short)f2bf(xb.y);
        xf[6] = (short)f2bf(xb.z); xf[7] = (short)f2bf(xb.w);
#pragma unroll
        for (int mt = 0; mt < 8; mt++) {
            bf16x8 wf = *(const bf16x8*)(sW + ((size_t)((mt * 8 + kc) * 64 + lane)) * 8);
            acc[mt] = __builtin_amdgcn_mfma_f32_16x16x32_bf16(wf, xf, acc[mt], 0, 0, 0);
        }
    }
    unsigned short* cp = C + (size_t)(row0 + r) * HDIM + quad * 4;
#pragma unroll
    for (int mt = 0; mt < 8; mt++) {
        u16x4 o;
#pragma unroll
        for (int j = 0; j < 4; j++) {
            float v = acc[mt][j];
            if (bias) v += bias[mt * 16 + quad * 4 + j];
            if (relu_out) v = fmaxf(v, 0.f);
            o[j] = f2bf(v);
        }
        *(u16x4*)(cp + mt * 16) = o;
    }
}

// ---------------- aggregate (R3 shape: quad layout, 8-deep 8B gathers, packed f32 adds) ----------------
__global__ __launch_bounds__(256) void k_aggregate_f8(
    const int* __restrict__ row_ptr, const int* __restrict__ col,
    const float* __restrict__ dis, const uint2* __restrict__ y8,
    const float* __restrict__ bias, unsigned short* __restrict__ out, int n, int relu_out)
{
    int wid = (blockIdx.x * 256 + threadIdx.x) >> 6;
    if (wid >= n) return;
    int lane = threadIdx.x & 63;
    int q = lane >> 4, t = lane & 15;
    f32x2 acc[4];
    {
        uint2 sv = y8[(size_t)wid * 16 + t];        // self term y[i]
        f32x2 p[4]; f8x8_decp(sv, p);
#pragma unroll
        for (int i = 0; i < 4; i++) acc[i] = (q == 0) ? p[i] : (f32x2){0.f, 0.f};
    }
    int beg = row_ptr[wid], end = row_ptr[wid + 1];
    int j = beg + q;
    // 8 independent gathers in flight
    for (; j + 28 < end; j += 32) {
        int s[8];
        uint2 v[8];
#pragma unroll
        for (int u = 0; u < 8; u++) s[u] = col[j + u * 4];
#pragma unroll
        for (int u = 0; u < 8; u++) v[u] = y8[(size_t)s[u] * 16 + t];
#pragma unroll
        for (int u = 0; u < 8; u++) {
            f32x2 p[4]; f8x8_decp(v[u], p);
#pragma unroll
            for (int i = 0; i < 4; i++) acc[i] += p[i];   // v_pk_add_f32
        }
    }
    for (; j + 12 < end; j += 16) {
        int s0 = col[j], s1 = col[j + 4], s2 = col[j + 8], s3 = col[j + 12];
        uint2 v0 = y8[(size_t)s0 * 16 + t];
        uint2 v1 = y8[(size_t)s1 * 16 + t];
        uint2 v2 = y8[(size_t)s2 * 16 + t];
        uint2 v3 = y8[(size_t)s3 * 16 + t];
        f32x2 p0[4], p1[4], p2[4], p3[4];
        f8x8_decp(v0, p0); f8x8_decp(v1, p1); f8x8_decp(v2, p2); f8x8_decp(v3, p3);
#pragma unroll
        for (int i = 0; i < 4; i++) acc[i] += (p0[i] + p1[i]) + (p2[i] + p3[i]);
    }
    for (; j < end; j += 4) {
        int s = col[j];
        uint2 v = y8[(size_t)s * 16 + t];
        f32x2 p[4]; f8x8_decp(v, p);
#pragma unroll
        for (int i = 0; i < 4; i++) acc[i] += p[i];
    }
#pragma unroll
    for (int i = 0; i < 4; i++) {
        acc[i].x += __shfl_xor(acc[i].x, 16, 64);
        acc[i].y += __shfl_xor(acc[i].y, 16, 64);
        acc[i].x += __shfl_xor(acc[i].x, 32, 64);
        acc[i].y += __shfl_xor(acc[i].y, 32, 64);
    }
    if (q == 0) {
        float di = dis[wid];
        u16x8 o;
#pragma unroll
        for (int i = 0; i < 4; i++) {
            float v0 = di * acc[i].x + bias[t * 8 + i * 2];
            float v1 = di * acc[i].y + bias[t * 8 + i * 2 + 1];
            if (relu_out) { v0 = fmaxf(v0, 0.f); v1 = fmaxf(v1, 0.f); }
            o[i * 2]     = f2bf(v0);
            o[i * 2 + 1] = f2bf(v1);
        }
        *(u16x8*)(out + (size_t)wid * HDIM + t * 8) = o;
    }
}

// ---------------- edge scorer: 8 groups of 8 lanes, 2-deep 16B gathers, fast sigmoid ----------------
__global__ __launch_bounds__(256) void k_edge_score_csr(
    const int* __restrict__ row_ptr, const uint2* __restrict__ epk,
    const uint4* __restrict__ P8, const uint4* __restrict__ Q8,
    const unsigned short* __restrict__ w2h, const float* __restrict__ b2,
    float* __restrict__ out, int n)
{
    int wid = (blockIdx.x * 256 + threadIdx.x) >> 6;
    if (wid >= n) return;
    int lane = threadIdx.x & 63;
    unsigned g = (unsigned)(lane >> 3), t = (unsigned)(lane & 7);
    f16x2 wh[8], qh[8];
    {
        uint4 wv0 = *(const uint4*)(w2h + t * 16);
        uint4 wv1 = *(const uint4*)(w2h + t * 16 + 8);
        wh[0] = __builtin_bit_cast(f16x2, wv0.x);
        wh[1] = __builtin_bit_cast(f16x2, wv0.y);
        wh[2] = __builtin_bit_cast(f16x2, wv0.z);
        wh[3] = __builtin_bit_cast(f16x2, wv0.w);
        wh[4] = __builtin_bit_cast(f16x2, wv1.x);
        wh[5] = __builtin_bit_cast(f16x2, wv1.y);
        wh[6] = __builtin_bit_cast(f16x2, wv1.z);
        wh[7] = __builtin_bit_cast(f16x2, wv1.w);
        uint4 qv = Q8[(unsigned)wid * 8u + t];   // Q row, sequential per node, shared by groups
        f8x16_dech(qv, qh);
    }
    float bb = b2[0];
    int beg = row_ptr[wid], end = row_ptr[wid + 1];
    int j = beg + (int)g;
    // 2 edges per group in flight (16 gathers/iter across wave) — R4/R6-verified shape
    for (; j + 8 < end; j += 16) {
        uint2 e0 = epk[j], e1 = epk[j + 8];
        uint4 p0 = P8[e0.x * 8u + t];
        uint4 p1 = P8[e1.x * 8u + t];
        float s0 = edot16(p0, qh, wh);
        float s1 = edot16(p1, qh, wh);
        s0 += __shfl_xor(s0, 4, 8); s1 += __shfl_xor(s1, 4, 8);
        s0 += __shfl_xor(s0, 2, 8); s1 += __shfl_xor(s1, 2, 8);
        s0 += __shfl_xor(s0, 1, 8); s1 += __shfl_xor(s1, 1, 8);
        // every lane of the group has both sums; lane t scores edge t
        float sv = (t == 0) ? s0 : s1;
        unsigned eid = (t == 0) ? e0.y : e1.y;
        if (t < 2)
            __builtin_nontemporal_store(fsigmoid(sv + bb), &out[eid]);   // NT: keep L2 for P
    }
    if (j < end) {
        uint2 e0 = epk[j];
        uint4 p0 = P8[e0.x * 8u + t];
        float s0 = edot16(p0, qh, wh);
        s0 += __shfl_xor(s0, 4, 8);
        s0 += __shfl_xor(s0, 2, 8);
        s0 += __shfl_xor(s0, 1, 8);
        if (t == 0)
            __builtin_nontemporal_store(fsigmoid(s0 + bb), &out[e0.y]);
    }
}

extern "C" void kernel_launch(void* const* d_in, const int* in_sizes, int n_in,
                              void* d_out, int out_size, void* d_ws, size_t ws_size,
                              hipStream_t stream) {
    const float* nf   = (const float*)d_in[0];
    const int*   ei   = (const int*)d_in[1];
    const float* ew1  = (const float*)d_in[2];
    const float* eb1  = (const float*)d_in[3];
    const float* ew2  = (const float*)d_in[4];
    const float* eb2  = (const float*)d_in[5];
    const float* cw1  = (const float*)d_in[6];
    const float* cb1  = (const float*)d_in[7];
    const float* cw2  = (const float*)d_in[8];
    const float* cb2  = (const float*)d_in[9];
    const float* cw3  = (const float*)d_in[10];
    const float* cb3  = (const float*)d_in[11];
    const float* clw1 = (const float*)d_in[12];
    const float* clb1 = (const float*)d_in[13];
    const float* clw2 = (const float*)d_in[14];
    const float* clb2 = (const float*)d_in[15];
    float* out = (float*)d_out;

    const int FD = 256;
    const int N = in_sizes[0] / FD;
    const int E = in_sizes[1] / 2;
    const int NBUCK = (N + 127) >> BSH;
    const int PBLK = 256;
    const int chunk = (E + PBLK - 1) / PBLK;

    size_t Np = ((size_t)N + 256) & ~(size_t)255;
    char* w = (char*)d_ws;
    float* dis     = (float*)w;            w += Np * 4;
    int*   tot     = (int*)w;              w += MAXBUCK * 4;
    int*   gcur    = (int*)w;              w += MAXBUCK * 4;
    int*   base    = (int*)w;              w += (MAXBUCK + 4) * 4;
    int*   hist    = (int*)w;              w += (size_t)PBLK * MAXBUCK * 4;
    int*   row_ptr = (int*)w;              w += Np * 4;
    uint2* stag    = (uint2*)w;            w += (size_t)E * 8;
    uint2* epk     = (uint2*)w;            w += (size_t)E * 8;
    int*   col     = (int*)w;              w += (((size_t)E * 4) + 255) & ~(size_t)255;
    unsigned short* bufA = (unsigned short*)w;  w += (size_t)N * HDIM * 2;
    unsigned short* bufB = (unsigned short*)w;  w += (size_t)N * HDIM * 2;
    unsigned short* bufC = (unsigned short*)w;  w += (size_t)N * HDIM * 2;
    unsigned char*  f8X  = (unsigned char*)w;   w += ((size_t)N * HDIM + 255) & ~(size_t)255;
    unsigned char*  f8P  = (unsigned char*)w;   w += ((size_t)N * HDIM + 255) & ~(size_t)255;
    unsigned char*  f8Q  = (unsigned char*)w;   w += ((size_t)N * HDIM + 255) & ~(size_t)255;
    unsigned short* wtE1 = (unsigned short*)w;  w += 256 * HDIM * 2;
    unsigned short* wtF  = (unsigned short*)w;  w += 128 * HDIM * 2;   // folded We2@Wc1
    unsigned short* wtC2 = (unsigned short*)w;  w += 128 * HDIM * 2;
    unsigned short* wtC3 = (unsigned short*)w;  w += 128 * HDIM * 2;
    unsigned short* wtT  = (unsigned short*)w;  w += 128 * HDIM * 2;
    unsigned short* wtB  = (unsigned short*)w;  w += 128 * HDIM * 2;
    unsigned short* w2h  = (unsigned short*)w;  w += 256 * 2;
    float*          bF   = (float*)w;           w += 128 * 4;

    int gemm_grid = (N + 63) / 64;
    int ag = (N + 3) / 4;

    // ---- weight prep + fold + tot zeroing (one dispatch) ----
    WAll wa;
    wa.w[0] = { ew1,               wtE1, 256 };
    wa.w[1] = { cw2,               wtC2, 128 };
    wa.w[2] = { cw3,               wtC3, 128 };
    wa.w[3] = { clw1,              wtT,  128 };
    wa.w[4] = { clw1 + 128 * HDIM, wtB,  128 };
    k_prep_all<<<dim3(128, 6), 256, 0, stream>>>(wa, ew2, eb2, cw1, wtF, bF, tot);

    // ---- CSR build (bucketed; col + epk grouped by dst node) ----
    k_hist<<<PBLK, 256, 0, stream>>>(ei + E, tot, hist, E, chunk, NBUCK);
    k_scan_buckets<<<1, 256, 0, stream>>>(tot, gcur, base, NBUCK, clw2, w2h);
    k_partition<<<PBLK, 256, 0, stream>>>(ei, ei + E, hist, gcur, stag, E, chunk, NBUCK);
    k_bucket_csr<<<NBUCK, 256, 0, stream>>>(base, stag, row_ptr, col, epk, dis, N, NBUCK);

    // ---- encoder stage 1 (bf16, relu) ----
    k_gemm_nf<<<gemm_grid, 256, 0, stream>>>(nf, wtE1, eb1, bufA, N, 1);

    // ---- conv1 (encoder-2 folded in): y = dis*(xe@W' + b') as fp8; aggregate -> bf16 ----
    k_gemm_b<<<gemm_grid, 256, 0, stream>>>(bufA, wtF, bF, dis, f8X, N, 0, 1);
    k_aggregate_f8<<<ag, 256, 0, stream>>>(row_ptr, col, dis, (const uint2*)f8X, cb1, bufC, N, 1);
    // ---- conv2 ----
    k_gemm_b<<<gemm_grid, 256, 0, stream>>>(bufC, wtC2, nullptr, dis, f8X, N, 0, 1);
    k_aggregate_f8<<<ag, 256, 0, stream>>>(row_ptr, col, dis, (const uint2*)f8X, cb2, bufA, N, 1);
    // ---- conv3 (no relu) ----
    k_gemm_b<<<gemm_grid, 256, 0, stream>>>(bufA, wtC3, nullptr, dis, f8X, N, 0, 1);
    k_aggregate_f8<<<ag, 256, 0, stream>>>(row_ptr, col, dis, (const uint2*)f8X, cb3, bufB, N, 0); // x3

    // ---- edge classifier: fused P/Q GEMM (X read once) ----
    k_gemm_pq<<<gemm_grid, 256, 0, stream>>>(bufB, wtT, wtB, clb1, f8P, f8Q, N);

    // ---- scorer: wave per dst node (Q streamed once per node, P random, NT out) ----
    k_edge_score_csr<<<ag, 256, 0, stream>>>(row_ptr, epk, (const uint4*)f8P, (const uint4*)f8Q,
                                             w2h, clb2, out, N);
}